// Round 1
// 91.954 us; speedup vs baseline: 1.1441x; 1.1441x over previous
//
#include <hip/hip_runtime.h>
#include <cmath>

#define KCLS 10
#define NCELL 3721          // 61*61
#define BIGV  0x0FFFFFFF

// d_out layout (all float32), concatenated in reference return order
#define OUT_PROB 0
#define OUT_LAB  37210
#define OUT_BOX  74420
#define OUT_VALID 223300

// ---------------------------------------------------------------------------
// DPP wave64 sum on the VALU pipe (v_add_f32_dpp) — avoids ds_bpermute (LDS
// pipe), which made the old __shfl_down reduction a ~9us LDS-pipe tail.
// LLVM-AtomicOptimizer / rocPRIM sequence; result lands in lane 63.
#define DPPADD(x, ctrl) \
    x += __int_as_float(__builtin_amdgcn_update_dpp( \
        0, __float_as_int(x), ctrl, 0xf, 0xf, true))

__device__ __forceinline__ float wave_sum64(float x) {
    DPPADD(x, 0x111);   // row_shr:1
    DPPADD(x, 0x112);   // row_shr:2
    DPPADD(x, 0x114);   // row_shr:4
    DPPADD(x, 0x118);   // row_shr:8
    DPPADD(x, 0x142);   // row_bcast:15
    DPPADD(x, 0x143);   // row_bcast:31
    return x;           // lane 63 holds the 64-lane sum
}

// Swizzled LDS float-index for W element j (row = j/10, col = j%10).
// Rows padded to 16 floats (64 B); 16B slot s of row r stored at s ^ ((r>>1)&3).
// With the 64B row stride this spreads a fixed-slot column read across all 32
// banks over every 8 consecutive rows -> conflict-free ds_read_b128/b64.
__device__ __forceinline__ int swz_fidx(int j) {
    const int row = j / 10;
    const int c   = j - row * 10;
    return (row << 4) + (((c >> 2) ^ ((row >> 1) & 3)) << 2) + (c & 3);
}

// ---------------- Stage 1: patch GEMM (+bias) + softmax --------------------
// 248 blocks x 1024 threads. Block = 2 patch-rows x 8 patch-cols (16 patches).
// Threads: tsub (256 d-lanes) x {wrow 0..1} x {dsl 0..1 K-slice}; per K-step a
// block consumes W rows [it*512, it*512+512) staged coalesced (dwordx4) into a
// swizzled, double-buffered LDS tile. P=8 patches/thread amortizes each
// 10-float W read over 80 FMAs so the LDS pipe stays under the FMA wall.
__global__ __launch_bounds__(1024) void k1_logits(
    const float* __restrict__ x, const float* __restrict__ W,
    const float* __restrict__ b, float* __restrict__ out)
{
    const int tid  = threadIdx.x;
    const int tsub = tid & 255;
    const int g    = tid >> 8;        // 0..3
    const int wrow = g & 1;           // patch-row within block
    const int dsl  = g >> 1;          // K-slice: d = tsub + dsl*256 + it*512
    const int blk  = blockIdx.x;
    const int rg   = blk >> 3;        // 0..30
    const int cg   = blk & 7;         // 0..7

    int r = rg * 2 + wrow; if (r > 60) r = 60;     // dup compute, write-guarded
    const int c0 = (cg == 7) ? 53 : cg * 8;        // cols c0..c0+7 all <= 60

    __shared__ float  wbuf[2][512 * 16];           // 64 KiB swizzled W tiles
    __shared__ float  red[2][2][4][8][KCLS];       // [wrow][dsl][wave][p][k]
    __shared__ double lgs[16][KCLS];

    // staging destinations (it-invariant): thread owns float4 @ j0 and float @ 4096+tid
    const int j0 = tid << 2;
    const int d0 = swz_fidx(j0);                   // b64 pair (j0, j0+1)  (j0%10 even)
    const int d1 = swz_fidx(j0 + 2);               // b64 pair (j0+2, j0+3)
    const int d2 = swz_fidx(4096 + tid);           // single float

    // compute-side read offsets (it-invariant)
    const int row = tsub + (dsl << 8);             // LDS row = W row within tile
    const int s3  = (row >> 1) & 3;
    const int rb  = row << 4;
    const int wo0 = rb + ((0 ^ s3) << 2);
    const int wo1 = rb + ((1 ^ s3) << 2);
    const int wo2 = rb + ((2 ^ s3) << 2);

    // x addressing: d = row + it*512 = i*192 + rem  (i = row-in-patch, rem = 3*j+ch)
    int i   = row / 192;
    int rem = row - i * 192;
    const float* xb = x + r * 49152 + c0 * 48;

    float acc[8][KCLS];
#pragma unroll
    for (int p = 0; p < 8; ++p)
#pragma unroll
        for (int k = 0; k < KCLS; ++k) acc[p][k] = 0.0f;

    // prologue: stage tile 0, prefetch tile 1 into regs
    float4 sv; float s1;
    {
        const float4 v0 = *(const float4*)(W + j0);
        const float  v1 = W[4096 + tid];
        float* wb0 = &wbuf[0][0];
        *(float2*)(wb0 + d0) = make_float2(v0.x, v0.y);
        *(float2*)(wb0 + d1) = make_float2(v0.z, v0.w);
        wb0[d2] = v1;
        const float* ws = W + 5120;
        sv = *(const float4*)(ws + j0);
        s1 = ws[4096 + tid];
    }

    for (int it = 0; it < 24; ++it) {
        __syncthreads();    // prev compute done -> safe to overwrite other buffer
        if (it + 1 < 24) {
            float* wbn = &wbuf[(it + 1) & 1][0];
            *(float2*)(wbn + d0) = make_float2(sv.x, sv.y);
            *(float2*)(wbn + d1) = make_float2(sv.z, sv.w);
            wbn[d2] = s1;
            if (it + 2 < 24) {   // issue-early: latency hides under compute
                const float* ws = W + (it + 2) * 5120;
                sv = *(const float4*)(ws + j0);
                s1 = ws[4096 + tid];
            }
        }
        // NOTE: no second barrier needed — wbuf[it&1] was fully written before
        // the barrier above (in iteration it-1); this iteration writes only
        // the other buffer.
        const float* wb = &wbuf[it & 1][0];
        const float4 wa  = *(const float4*)(wb + wo0);
        const float4 wbq = *(const float4*)(wb + wo1);
        const float2 wc  = *(const float2*)(wb + wo2);
        const float wv[KCLS] = { wa.x, wa.y, wa.z, wa.w,
                                 wbq.x, wbq.y, wbq.z, wbq.w, wc.x, wc.y };
        const float* xp = xb + i * 3072 + rem;
        float xv[8];
#pragma unroll
        for (int p = 0; p < 8; ++p) xv[p] = xp[p * 48];   // immediate offsets
#pragma unroll
        for (int p = 0; p < 8; ++p)
#pragma unroll
            for (int k = 0; k < KCLS; ++k) acc[p][k] += xv[p] * wv[k];

        rem += 128; i += 2;                 // d += 512
        if (rem >= 192) { rem -= 192; ++i; }
    }

    // wave reduction (VALU pipe), partials to LDS
    const int w4 = tsub >> 6;
#pragma unroll
    for (int p = 0; p < 8; ++p)
#pragma unroll
        for (int k = 0; k < KCLS; ++k) {
            const float s = wave_sum64(acc[p][k]);
            if ((tid & 63) == 63) red[wrow][dsl][w4][p][k] = s;
        }
    __syncthreads();

    if (tid < 160) {
        const int wr  = tid / 80;
        const int t80 = tid - wr * 80;
        const int p   = t80 / 10;
        const int kk  = t80 - p * 10;
        double s = (double)b[kk];
#pragma unroll
        for (int ds = 0; ds < 2; ++ds)
#pragma unroll
            for (int w = 0; w < 4; ++w) s += (double)red[wr][ds][w][p][kk];
        lgs[wr * 8 + p][kk] = s;
    }
    __syncthreads();

    if (tid < 16) {
        const int wr = tid >> 3, p = tid & 7;
        const int rr = rg * 2 + wr, cc = c0 + p;
        if (rr <= 60) {                     // cc always <= 60; dup cols benign (bit-identical)
            double l[KCLS];
#pragma unroll
            for (int k = 0; k < KCLS; ++k) l[k] = lgs[tid][k];
            double m = l[0];
#pragma unroll
            for (int k = 1; k < KCLS; ++k) m = fmax(m, l[k]);
            double e[KCLS], ssum = 0.0;
#pragma unroll
            for (int k = 0; k < KCLS; ++k) { e[k] = exp(l[k] - m); ssum += e[k]; }
            const double inv = 1.0 / ssum;
            float* po = out + OUT_PROB + (size_t)(rr * 61 + cc) * KCLS;
#pragma unroll
            for (int k = 0; k < KCLS; ++k) po[k] = (float)(e[k] * inv);
        }
    }
}

// ---------------- Stage 2+3 fused: CC (union-find hooking) + boxes ---------
// One block per class. Reference fixed point = per-component min cell-index.
// Labels stored as LDS OFFSETS (off = (r+1)*64 + c+1): min-off == min-idx
// (both lexicographic in (r,c)), so root chasing needs no div-by-61.
// Root chase + atomicMin hooking = path compression -> ~3-6 rounds instead of
// O(component diameter) rounds of plain Gauss-Seidel.
__global__ __launch_bounds__(1024) void k2_cc_boxes(float* __restrict__ out)
{
    const int k   = blockIdx.x;
    const int tid = threadIdx.x;

    __shared__ int lab[63 * 64];
    __shared__ int act[NCELL];
    __shared__ int nact, changed;
    __shared__ int rmn[NCELL + 1], rmx[NCELL + 1], cmn[NCELL + 1], cmx[NCELL + 1];

    for (int idx = tid; idx < 63 * 64; idx += 1024) lab[idx] = BIGV;
    for (int s = tid; s <= NCELL; s += 1024) {
        rmn[s] = 0x7fffffff; cmn[s] = 0x7fffffff; rmx[s] = -1; cmx[s] = -1;
    }
    if (tid == 0) nact = 0;
    __syncthreads();

    for (int idx = tid; idx < NCELL; idx += 1024) {
        const float pv = out[OUT_PROB + (size_t)idx * KCLS + k];
        if (pv > 0.7f) {
            const int r = idx / 61, c = idx - r * 61;
            const int off = (r + 1) * 64 + (c + 1);
            lab[off] = off;
            act[atomicAdd(&nact, 1)] = off;
        }
    }
    __syncthreads();
    const int na = nact;

    for (int round = 0; round < 128; ++round) {
        if (tid == 0) changed = 0;
        __syncthreads();
        bool ch = false;
        for (int ii = tid; ii < na; ii += 1024) {
            const int off = act[ii];
            const int v = lab[off];
            int m = v, t;
            t = lab[off - 1];  if (t < m) m = t;
            t = lab[off + 1];  if (t < m) m = t;
            t = lab[off - 64]; if (t < m) m = t;
            t = lab[off + 64]; if (t < m) m = t;
            if (m < v) {
                int p = lab[m];                       // chase to current root
                while (p < m) { m = p; p = lab[m]; }  // strictly decreasing -> terminates
                atomicMin(&lab[off], m);              // compress self
                atomicMin(&lab[v],   m);              // hook old root (union)
                ch = true;
            }
        }
        if (ch) changed = 1;       // benign race
        __syncthreads();
        if (changed == 0) break;   // no writes between the barriers -> uniform
        __syncthreads();           // protect next round's reset
    }

    // write labels (convert off -> idx+1)
    for (int idx = tid; idx < NCELL; idx += 1024) {
        const int r = idx / 61, c = idx - r * 61;
        const int v = lab[(r + 1) * 64 + (c + 1)];
        const int lv = (v < BIGV) ? ((v >> 6) * 61 - 61 + (v & 63)) : 0;
        out[OUT_LAB + (size_t)idx * KCLS + k] = (float)lv;
    }

    // boxes: segment min/max over active cells only
    for (int ii = tid; ii < na; ii += 1024) {
        const int off = act[ii];
        const int v = lab[off];
        const int lb = (v >> 6) * 61 - 61 + (v & 63);
        const int r = (off >> 6) - 1, c = (off & 63) - 1;
        atomicMin(&rmn[lb], r); atomicMax(&rmx[lb], r);
        atomicMin(&cmn[lb], c); atomicMax(&cmx[lb], c);
    }
    __syncthreads();

    for (int s = tid; s <= NCELL; s += 1024) {
        const bool val = (s > 0) && (rmx[s] >= 0);
        float* bo = out + OUT_BOX + (size_t)(k * (NCELL + 1) + s) * 4;
        if (val) {
            bo[0] = (float)(rmn[s] - 1);
            bo[1] = (float)(cmn[s] - 1);
            bo[2] = (float)(rmx[s] + 1);
            bo[3] = (float)(cmx[s] + 1);
        } else {
            bo[0] = 0.0f; bo[1] = 0.0f; bo[2] = 0.0f; bo[3] = 0.0f;
        }
        out[OUT_VALID + (size_t)k * (NCELL + 1) + s] = val ? 1.0f : 0.0f;
    }
}

extern "C" void kernel_launch(void* const* d_in, const int* in_sizes, int n_in,
                              void* d_out, int out_size, void* d_ws, size_t ws_size,
                              hipStream_t stream) {
    const float* x = (const float*)d_in[0];   // (1,1024,1024,3) f32
    const float* W = (const float*)d_in[1];   // (12288,10) f32
    const float* b = (const float*)d_in[2];   // (10,) f32
    float* out = (float*)d_out;

    k1_logits  <<<dim3(248), dim3(1024), 0, stream>>>(x, W, b, out);
    k2_cc_boxes<<<dim3(KCLS), dim3(1024), 0, stream>>>(out);
}